// Round 12
// baseline (339.455 us; speedup 1.0000x reference)
//
#include <hip/hip_runtime.h>
#include <math.h>

// ---------------------------------------------------------------------------
// AttentionNet round 20: r18 core (328.5-337.9 us measured band) + CORRECTED
// parallel L2 prefetch. r19's prefetch failed because `pf += volatile-load`
// serialized 8 dependent misses per iter (58 us/dispatch). Corrected test of
// the latency model: ONE independent u32 load per thread per K-iter
// (256 threads <-> 256 lines: tid<128 -> A row tid, else B row tid-128;
// each row's next 128B K-slice = one aligned L2 line; the XOR swizzle stays
// within that line). Issued after the first sync, drained by the SECOND
// __syncthreads' existing implicit vmcnt(0) (after ~550cy of MFMA); the asm
// sink sits after the barrier so it adds no wait. Next iter's
// global_load_lds then hit L2 (~200cy) instead of missing (~900cy).
// Everything else byte-identical to the verified r18 kernel.
// Pre-registered: 305-325 us confirms the latency model; 330-340 falsifies
// it (then declare plateau); >345 revert.
// ---------------------------------------------------------------------------

typedef __attribute__((ext_vector_type(8))) int i32x8;
typedef __attribute__((ext_vector_type(4))) int i32x4;
typedef __attribute__((ext_vector_type(4))) float f32x4;
typedef unsigned char u8;
typedef unsigned int u32;

#define EPI_F8 1
#define EPI_RV 2
#define EPI_EXP 3
#define EPI_PV 4
#define EPI_EXPF32 5

__device__ __forceinline__ void gload_lds16(const void* g, void* l) {
    __builtin_amdgcn_global_load_lds(
        (const __attribute__((address_space(1))) void*)g,
        (__attribute__((address_space(3))) void*)l, 16, 0, 0);
}

__device__ __forceinline__ u8 cvt_f8(float v) {
    return (u8)(__builtin_amdgcn_cvt_pk_fp8_f32(v, v, 0, false) & 0xFF);
}

__device__ __forceinline__ u32 pack_f8x4(float v0, float v1, float v2, float v3) {
    int p01 = __builtin_amdgcn_cvt_pk_fp8_f32(v0, v1, 0, false);
    int p23 = __builtin_amdgcn_cvt_pk_fp8_f32(v2, v3, 0, false);
    return (u32)(p01 & 0xFFFF) | ((u32)p23 << 16);
}

// C = epilogue(alpha * (A @ B^T)); A=[MA,K] fp8 (weight/key/VT side),
// B=[NB,K] fp8 (token side), batch=blockIdx.z. K % 128 == 0.
// Output row-major [B-row][A-row]: lane's 4 regs = 4 consecutive A-rows.
template <int EPI>
__global__ __launch_bounds__(256) void gemm_fp8(
    const u8* __restrict__ A, const u8* __restrict__ B,
    void* __restrict__ C0, void* __restrict__ C1, void* __restrict__ C2,
    int K, int ldA, int ldB, int ldC,
    long long bsA, long long bsB, long long bsC, float alpha, float beta)
{
    __shared__ u8 sA[128 * 128];
    __shared__ u8 sB[128 * 128];

    const int tid = threadIdx.x;
    const int wave = tid >> 6, lane = tid & 63;
    const int wm = wave >> 1, wn = wave & 1;
    const int m0 = blockIdx.y * 128, n0 = blockIdx.x * 128;
    const long long z = blockIdx.z;

    const u8* pA = A + z * bsA;
    const u8* pB = B + z * bsB;

    // Tile = 128 rows x 8 16B-chunks. LDS chunk (row,c) holds global chunk
    // c ^ (row&7). global_load_lds dst must be wave-uniform base + lane*16.
    int blkid[4], rs_[4], cs16[4];
#pragma unroll
    for (int i = 0; i < 4; i++) {
        blkid[i] = wave * 256 + i * 64 + lane;
        rs_[i] = blkid[i] >> 3;
        cs16[i] = ((blkid[i] & 7) ^ (rs_[i] & 7)) * 16;
    }

    // Prefetch address base: one 128B line per thread (A rows for tid<128,
    // B rows for tid>=128); rows are 128B-aligned at every k0.
    const int prow = tid & 127;
    const u8* pfp = (tid < 128)
        ? pA + (long long)(m0 + prow) * ldA
        : pB + (long long)(n0 + prow) * ldB;

    f32x4 acc[4][4] = {};
    const int fr = lane & 15, fc2 = (lane >> 4) * 2;

    for (int k0 = 0; k0 < K; k0 += 128) {
#pragma unroll
        for (int i = 0; i < 4; i++) {
            gload_lds16(pA + (long long)(m0 + rs_[i]) * ldA + k0 + cs16[i],
                        sA + blkid[i] * 16);
            gload_lds16(pB + (long long)(n0 + rs_[i]) * ldB + k0 + cs16[i],
                        sB + blkid[i] * 16);
        }
        __syncthreads();

        // Independent L2 prefetch of next K-slice (one load/thread, no
        // dependent chain). Drained by the second __syncthreads' existing
        // vmcnt(0) after the MFMA block - no added wait.
        u32 pf = 0;
        if (k0 + 128 < K)
            pf = *(const u32*)(pfp + k0 + 128);

        i32x8 a[4], b[4];
#pragma unroll
        for (int i = 0; i < 4; i++) {
            const int row = wm * 64 + i * 16 + fr;
            const int sw = row & 7;
            i32x4 lo = *(const i32x4*)(sA + row * 128 + ((fc2 + 0) ^ sw) * 16);
            i32x4 hi = *(const i32x4*)(sA + row * 128 + ((fc2 + 1) ^ sw) * 16);
            a[i] = __builtin_shufflevector(lo, hi, 0, 1, 2, 3, 4, 5, 6, 7);
        }
#pragma unroll
        for (int j = 0; j < 4; j++) {
            const int row = wn * 64 + j * 16 + fr;
            const int sw = row & 7;
            i32x4 lo = *(const i32x4*)(sB + row * 128 + ((fc2 + 0) ^ sw) * 16);
            i32x4 hi = *(const i32x4*)(sB + row * 128 + ((fc2 + 1) ^ sw) * 16);
            b[j] = __builtin_shufflevector(lo, hi, 0, 1, 2, 3, 4, 5, 6, 7);
        }
#pragma unroll
        for (int i = 0; i < 4; i++)
#pragma unroll
            for (int j = 0; j < 4; j++)
                acc[i][j] = __builtin_amdgcn_mfma_scale_f32_16x16x128_f8f6f4(
                    a[i], b[j], acc[i][j], 0 /*A=e4m3*/, 0 /*B=e4m3*/,
                    0, 0x7F7F7F7F, 0, 0x7F7F7F7F);
        __syncthreads();
        asm volatile("" :: "v"(pf));   // keep pf live; already drained above
    }

    const int col = lane & 15;         // B-row offset within 16-tile
    const int rbase = (lane >> 4) * 4; // first of 4 consecutive A-rows

    if (EPI == EPI_EXP) {
        // P[z][q][key] = fp8(exp(acc*alpha)/16) packed u32; rsum[q] += sum e
        u8* P = (u8*)C0 + z * bsC;
        float* rsum = (float*)C1 + z * 2048;
#pragma unroll
        for (int j = 0; j < 4; j++) {
            const int Cq = n0 + wn * 64 + j * 16 + col;
            float part = 0.f;
#pragma unroll
            for (int i = 0; i < 4; i++) {
                const int R0 = m0 + wm * 64 + i * 16 + rbase;
                float e0 = __expf(acc[i][j][0] * alpha);
                float e1 = __expf(acc[i][j][1] * alpha);
                float e2 = __expf(acc[i][j][2] * alpha);
                float e3 = __expf(acc[i][j][3] * alpha);
                part += (e0 + e1) + (e2 + e3);
                *(u32*)(P + (long long)Cq * ldC + R0) =
                    pack_f8x4(e0 * 0.0625f, e1 * 0.0625f,
                              e2 * 0.0625f, e3 * 0.0625f);
            }
            part += __shfl_xor(part, 16);
            part += __shfl_xor(part, 32);
            if (lane < 16) atomicAdd(&rsum[Cq], part);
        }
        return;
    }

    if (EPI == EPI_EXPF32) {
        // E[token][class] = exp(acc*alpha) float4; rsum[token] += sum
        float* Cw = (float*)C0;
        float* rsum = (float*)C1;
#pragma unroll
        for (int j = 0; j < 4; j++) {
            const int Cq = n0 + wn * 64 + j * 16 + col;
            float part = 0.f;
#pragma unroll
            for (int i = 0; i < 4; i++) {
                const int R0 = m0 + wm * 64 + i * 16 + rbase;
                float4 e;
                e.x = __expf(acc[i][j][0] * alpha);
                e.y = __expf(acc[i][j][1] * alpha);
                e.z = __expf(acc[i][j][2] * alpha);
                e.w = __expf(acc[i][j][3] * alpha);
                part += (e.x + e.y) + (e.z + e.w);
                *(float4*)(Cw + (long long)Cq * ldC + R0) = e;
            }
            part += __shfl_xor(part, 16);
            part += __shfl_xor(part, 32);
            if (lane < 16) atomicAdd(&rsum[Cq], part);
        }
        return;
    }

#pragma unroll
    for (int j = 0; j < 4; j++) {
        const int Cq = n0 + wn * 64 + j * 16 + col;
        float inv;
        if (EPI == EPI_PV) {
            const float* rsum = (const float*)C1 + z * 2048;
            inv = alpha / rsum[Cq];
        }
#pragma unroll
        for (int i = 0; i < 4; i++) {
            const int R0 = m0 + wm * 64 + i * 16 + rbase;
            if (EPI == EPI_F8) {
                u8* C = (u8*)C0 + z * bsC;
                *(u32*)(C + (long long)Cq * ldC + R0) =
                    pack_f8x4(acc[i][j][0] * alpha, acc[i][j][1] * alpha,
                              acc[i][j][2] * alpha, acc[i][j][3] * alpha);
            } else if (EPI == EPI_PV) {
                u8* C = (u8*)C0 + z * bsC;
                float v[4];
#pragma unroll
                for (int r = 0; r < 4; r++) {
                    float t = acc[i][j][r] * inv;
                    v[r] = (t / (1.f + __expf(-t))) * beta;   // silu * beta
                }
                *(u32*)(C + (long long)Cq * ldC + R0) =
                    pack_f8x4(v[0], v[1], v[2], v[3]);
            } else { // EPI_RV: A-rows 0..1023 -> R (alpha), 1024.. -> V^T (beta)
                const int seg = R0 >> 10;
                const int db = R0 & 1023;
                if (seg == 1) {
                    // V^T[bb][d][token], byte scatter over 4 d-rows
                    const int bb = Cq >> 11, tt = Cq & 2047;
                    u8* VTp = (u8*)C2;
#pragma unroll
                    for (int r = 0; r < 4; r++)
                        VTp[(long long)bb * (1024LL * 2048) +
                            (long long)(db + r) * 2048 + tt] =
                            cvt_f8(acc[i][j][r] * beta);
                } else {
                    u8* C = (u8*)C0;
                    *(u32*)(C + (long long)Cq * 1024 + db) =
                        pack_f8x4(acc[i][j][0] * alpha, acc[i][j][1] * alpha,
                                  acc[i][j][2] * alpha, acc[i][j][3] * alpha);
                }
            }
        }
    }
}

// Fused convert: blocks 0..8191 = x -> fp8 (scale 8); 8192..12287 = wv1|wv2|
// fc1|fc2 -> fp8 (scale 256); 12288..13311 = transpose-convert wq1|wk1|wq2|
// wk2 -> fp8^T (scale 256, 64x64 tiles); blocks 0..23 also zero the 3 rsum
// buffers (24576 floats at rz).
__global__ __launch_bounds__(256) void convert_fused(
    const float* x, const float* wv1, const float* wv2, const float* fc1,
    const float* fc2, const float* wq1, const float* wk1, const float* wq2,
    const float* wk2, u8* __restrict__ ax, u8* __restrict__ bproj,
    u8* __restrict__ wfc, u8* __restrict__ wqT, float* __restrict__ rz)
{
    const int bid = blockIdx.x;
    if (bid < 24) {
        float4 zero = {0.f, 0.f, 0.f, 0.f};
        *(float4*)(rz + ((long long)bid * 256 + threadIdx.x) * 4) = zero;
    }
    if (bid >= 12288) {
        // transpose path (old convert_t): 256 tiles per matrix
        const int idx2 = bid - 12288;
        const float* srcs[4] = {wq1, wk1, wq2, wk2};
        const float* src = srcs[idx2 >> 8];
        u8* dst = wqT + (long long)(idx2 >> 8) * (1 << 20);
        const int tile = idx2 & 255;
        const int q0 = (tile & 15) * 64, d0 = (tile >> 4) * 64;
        const int qq = (threadIdx.x & 15) * 4, dd = (threadIdx.x >> 4) * 4;
        float4 v[4];
#pragma unroll
        for (int s = 0; s < 4; s++)
            v[s] = *(const float4*)(src + (long long)(q0 + qq + s) * 1024 + d0 + dd);
        const float* vf = (const float*)v;   // vf[s*4 + r]
#pragma unroll
        for (int r = 0; r < 4; r++)
            *(u32*)(dst + (long long)(d0 + dd + r) * 1024 + q0 + qq) =
                pack_f8x4(vf[0 * 4 + r] * 256.f, vf[1 * 4 + r] * 256.f,
                          vf[2 * 4 + r] * 256.f, vf[3 * 4 + r] * 256.f);
        return;
    }
    const float* src;
    u8* dst;
    float scale;
    long long i;
    if (bid < 8192) {
        src = x; dst = ax; scale = 8.f;
        i = ((long long)bid * 256 + threadIdx.x) * 4;
    } else {
        const int idx = bid - 8192;
        const int wi = idx >> 10;
        const float* srcs[4] = {wv1, wv2, fc1, fc2};
        // wv1 -> Bproj[0] rows 1024+, wv2 -> Bproj[1] rows 1024+, fc -> Wfc
        u8* dsts[4] = {bproj + (1 << 20), bproj + 3 * (1 << 20),
                       wfc, wfc + (1 << 20)};
        src = srcs[wi]; dst = dsts[wi]; scale = 256.f;
        i = (((long long)(idx & 1023)) * 256 + threadIdx.x) * 4;
    }
    float4 v = *(const float4*)(src + i);
    *(u32*)(dst + i) = pack_f8x4(v.x * scale, v.y * scale,
                                 v.z * scale, v.w * scale);
}

// out[row][c] = e[row][c] / rsum[row]  (1024 cols, fp32)
__global__ __launch_bounds__(256) void normalize_1024(
    const float* __restrict__ e, const float* __restrict__ rsum,
    float* __restrict__ out)
{
    const long long row = blockIdx.x;
    const float inv = 1.0f / rsum[row];
    const float* p = e + row * 1024;
    float* o = out + row * 1024;
    float4 v = *(const float4*)(p + threadIdx.x * 4);
    float4 ov;
    ov.x = v.x * inv; ov.y = v.y * inv; ov.z = v.z * inv; ov.w = v.w * inv;
    *(float4*)(o + threadIdx.x * 4) = ov;
}

extern "C" void kernel_launch(void* const* d_in, const int* in_sizes, int n_in,
                              void* d_out, int out_size, void* d_ws, size_t ws_size,
                              hipStream_t stream)
{
    float* out = (float*)d_out;

    constexpr int Bt = 4, S = 2048, D = 1024;
    constexpr int M = Bt * S;                  // 8192
    const long long MD = (long long)M * D;     // 8,388,608
    const long long DD = (long long)D * D;
    const long long SD = (long long)S * D;
    const long long SS = (long long)S * S;

    // ws: Af 8MB | Bproj 2x2MB | WqT 4x1MB | Wfc 2x1MB | Rf 8MB | VT 8MB |
    // Pf 16MB | Hs 8MB | SC fp32 32MB | rsum0|1|2
    u8* Af = (u8*)d_ws;
    u8* Bproj = Af + MD;                 // [2][2048][1024]: WqkT | wv
    u8* WqT = Bproj + 2 * 2048 * 1024;   // wq1T | wk1T | wq2T | wk2T
    u8* Wfc = WqT + 4 * DD;              // fc1 | fc2
    u8* Rf = Wfc + 2 * DD;
    u8* VT = Rf + MD;
    u8* Pf = VT + MD;
    u8* Hs = Pf + (long long)Bt * SS;
    float* SC = (float*)(Hs + MD);
    float* rsum0 = SC + MD;
    float* rsum1 = rsum0 + M;
    float* rsum2 = rsum1 + M;

    const dim3 blk(256);

    const float SOFT = 0.08838834764831845f; // 1/sqrt(128)
    // scale-fold alphas (all pow2 exact):
    const float a_d1   = 1.f / 64.f;               // WqkT: 256*256 -> 1024
    const float a_R[2] = {1.f / 512.f, 1.f / 1024.f};  // R1: 8*1024->16; R2: 256*1024->256
    const float b_V[2] = {1.f / 256.f, 1.f / 64.f};    // V1: 8*256->8; V2: 256*256->1024
    const float a_qk[2] = {SOFT / 128.f, SOFT / 65536.f}; // R*act scales
    const float a_pv[2] = {2.0f, 1.f / 64.f};      // 16 / V-scale, then /rsum
    const float b_pv[2] = {256.f, 65536.f};        // Hs store scale
    const float a_fc[2] = {256.f / 65536.f, 1.f / 16777216.f};

    convert_fused<<<dim3(13312), blk, 0, stream>>>(
        (const float*)d_in[0], (const float*)d_in[3], (const float*)d_in[7],
        (const float*)d_in[4], (const float*)d_in[8], (const float*)d_in[1],
        (const float*)d_in[2], (const float*)d_in[5], (const float*)d_in[6],
        Af, Bproj, Wfc, WqT, rsum0);
    // Bproj[z] rows 0..1023 = WqkT_z = P(A=wqT_z, B=wkT_z), stored scale 1024
    gemm_fp8<EPI_F8><<<dim3(8, 8, 2), blk, 0, stream>>>(
        WqT, WqT + DD, Bproj, nullptr, nullptr, D, D, D, D,
        2 * DD, 2 * DD, (long long)2048 * 1024, a_d1, 0.f);

    const dim3 grv(M / 128, 2048 / 128, 1);    // [R|V] projection (64,16)
    const dim3 gqk(S / 128, S / 128, Bt);      // scores: x = queries, y = keys
    const dim3 gpv(S / 128, D / 128, Bt);      // x = tokens, y = d-tiles
    const dim3 gw(M / 128, D / 128, 1);        // fc GEMMs (64,8)

    for (int layer = 0; layer < 2; layer++) {
        const u8* bp = Bproj + (long long)layer * 2048 * 1024;
        const u8* fc = Wfc + (long long)layer * DD;
        float* rsum = layer ? rsum1 : rsum0;

        // R[t][j] (Rf, packed u32) and V^T[b][d][t] (VT, scatter)
        gemm_fp8<EPI_RV><<<grv, blk, 0, stream>>>(
            bp, Af, Rf, nullptr, VT, D, D, D, D, 0, 0, 0,
            a_R[layer], b_V[layer]);
        // P[z][q][key] = fp8(exp(score)/16); rsum[q] = sum exp.
        // keys side = activations themselves (Af), queries side = R.
        gemm_fp8<EPI_EXP><<<gqk, blk, 0, stream>>>(
            Af, Rf, Pf, rsum, nullptr, D, D, D, S, SD, SD, SS,
            a_qk[layer], 0.f);
        // Hs[token][d] = fp8(silu(P@V / rsum) * b_pv)
        gemm_fp8<EPI_PV><<<gpv, blk, 0, stream>>>(
            VT, Pf, Hs, rsum, nullptr, S, S, S, D,
            (long long)D * S, SS, SD, a_pv[layer], b_pv[layer]);
        if (layer == 0) {
            gemm_fp8<EPI_F8><<<gw, blk, 0, stream>>>(
                fc, Hs, Af, nullptr, nullptr, D, D, D, D, 0, 0, 0,
                a_fc[0], 0.f);
        } else {
            gemm_fp8<EPI_EXPF32><<<gw, blk, 0, stream>>>(
                fc, Hs, SC, rsum2, nullptr, D, D, D, D, 0, 0, 0,
                a_fc[1], 0.f);
        }
    }

    normalize_1024<<<dim3(M), blk, 0, stream>>>(SC, rsum2, out);
}

// Round 13
// 335.639 us; speedup vs baseline: 1.0114x; 1.0114x over previous
//
#include <hip/hip_runtime.h>
#include <math.h>

// ---------------------------------------------------------------------------
// AttentionNet FINAL: the verified r18 kernel (measured band 328.5-339.5 us
// across four runs; best 328.5). 11 dispatches.
//
// Session summary (r10-r20, every hypothesis pre-registered + measured):
//   - GEMM core variants: single/double/triple buffer x prefetch depth 0/1/2
//     x fine/coarse counted-vmcnt phases x tiles 64/128/256 x 1/2/5 blocks/CU
//     x +-XCD swizzle x L2 software prefetch (serial AND parallel forms):
//     ALL regressed or neutral vs this 128x128 single-buffered max-TLP core.
//   - Per-dispatch time is invariant to schedule AND staged bytes; all pipes
//     read 13-20% (Mfma/VALU/HBM/Occ). The floor is inter-dispatch
//     production->consumption latency under barrier phase-lock:
//     8 serial GEMMs x (8 K-iters x ~900cy miss + epilogue) ~ 280 us
//     + ~55 us convert/Wqk/normalize = the measured 330 us band.
//   - Algebraic levers closed: EXP+PV flash-fusion register-infeasible at
//     D=1024; fc1-folding needs 3 serial 1024^3 weight GEMMs (net negative).
//   - Breaching the wall requires a persistent cooperative mega-kernel
//     (keeps activations L2-resident across stages) - a rewrite, not polish.
//
// Structure: QK^T reassociation scores = (x@Wqk)@x^T with Wqk = wq^T wk
// precomputed per layer; Q/K never materialized (projection = [R|V], EXP's
// key operand is the activation buffer). GEMM core: 16x16x128 MX-fp8 e4m3,
// 128x128 tile, XOR-swizzled LDS (0 bank conflicts), global_load_lds(16),
// 5 blocks/CU. Scales (pow2, exact): x*8, w*256, WqkT*1024, R1*16, R2*256,
// V1*8, V2*1024, P=expS/16, Hs1*256, Hs2*65536, h2*256.
// ---------------------------------------------------------------------------

typedef __attribute__((ext_vector_type(8))) int i32x8;
typedef __attribute__((ext_vector_type(4))) int i32x4;
typedef __attribute__((ext_vector_type(4))) float f32x4;
typedef unsigned char u8;
typedef unsigned int u32;

#define EPI_F8 1
#define EPI_RV 2
#define EPI_EXP 3
#define EPI_PV 4
#define EPI_EXPF32 5

__device__ __forceinline__ void gload_lds16(const void* g, void* l) {
    __builtin_amdgcn_global_load_lds(
        (const __attribute__((address_space(1))) void*)g,
        (__attribute__((address_space(3))) void*)l, 16, 0, 0);
}

__device__ __forceinline__ u8 cvt_f8(float v) {
    return (u8)(__builtin_amdgcn_cvt_pk_fp8_f32(v, v, 0, false) & 0xFF);
}

__device__ __forceinline__ u32 pack_f8x4(float v0, float v1, float v2, float v3) {
    int p01 = __builtin_amdgcn_cvt_pk_fp8_f32(v0, v1, 0, false);
    int p23 = __builtin_amdgcn_cvt_pk_fp8_f32(v2, v3, 0, false);
    return (u32)(p01 & 0xFFFF) | ((u32)p23 << 16);
}

// C = epilogue(alpha * (A @ B^T)); A=[MA,K] fp8 (weight/key/VT side),
// B=[NB,K] fp8 (token side), batch=blockIdx.z. K % 128 == 0.
// Output row-major [B-row][A-row]: lane's 4 regs = 4 consecutive A-rows.
template <int EPI>
__global__ __launch_bounds__(256) void gemm_fp8(
    const u8* __restrict__ A, const u8* __restrict__ B,
    void* __restrict__ C0, void* __restrict__ C1, void* __restrict__ C2,
    int K, int ldA, int ldB, int ldC,
    long long bsA, long long bsB, long long bsC, float alpha, float beta)
{
    __shared__ u8 sA[128 * 128];
    __shared__ u8 sB[128 * 128];

    const int tid = threadIdx.x;
    const int wave = tid >> 6, lane = tid & 63;
    const int wm = wave >> 1, wn = wave & 1;
    const int m0 = blockIdx.y * 128, n0 = blockIdx.x * 128;
    const long long z = blockIdx.z;

    const u8* pA = A + z * bsA;
    const u8* pB = B + z * bsB;

    // Tile = 128 rows x 8 16B-chunks. LDS chunk (row,c) holds global chunk
    // c ^ (row&7). global_load_lds dst must be wave-uniform base + lane*16.
    int blkid[4], rs_[4], cs16[4];
#pragma unroll
    for (int i = 0; i < 4; i++) {
        blkid[i] = wave * 256 + i * 64 + lane;
        rs_[i] = blkid[i] >> 3;
        cs16[i] = ((blkid[i] & 7) ^ (rs_[i] & 7)) * 16;
    }

    f32x4 acc[4][4] = {};
    const int fr = lane & 15, fc2 = (lane >> 4) * 2;

    for (int k0 = 0; k0 < K; k0 += 128) {
#pragma unroll
        for (int i = 0; i < 4; i++) {
            gload_lds16(pA + (long long)(m0 + rs_[i]) * ldA + k0 + cs16[i],
                        sA + blkid[i] * 16);
            gload_lds16(pB + (long long)(n0 + rs_[i]) * ldB + k0 + cs16[i],
                        sB + blkid[i] * 16);
        }
        __syncthreads();

        i32x8 a[4], b[4];
#pragma unroll
        for (int i = 0; i < 4; i++) {
            const int row = wm * 64 + i * 16 + fr;
            const int sw = row & 7;
            i32x4 lo = *(const i32x4*)(sA + row * 128 + ((fc2 + 0) ^ sw) * 16);
            i32x4 hi = *(const i32x4*)(sA + row * 128 + ((fc2 + 1) ^ sw) * 16);
            a[i] = __builtin_shufflevector(lo, hi, 0, 1, 2, 3, 4, 5, 6, 7);
        }
#pragma unroll
        for (int j = 0; j < 4; j++) {
            const int row = wn * 64 + j * 16 + fr;
            const int sw = row & 7;
            i32x4 lo = *(const i32x4*)(sB + row * 128 + ((fc2 + 0) ^ sw) * 16);
            i32x4 hi = *(const i32x4*)(sB + row * 128 + ((fc2 + 1) ^ sw) * 16);
            b[j] = __builtin_shufflevector(lo, hi, 0, 1, 2, 3, 4, 5, 6, 7);
        }
#pragma unroll
        for (int i = 0; i < 4; i++)
#pragma unroll
            for (int j = 0; j < 4; j++)
                acc[i][j] = __builtin_amdgcn_mfma_scale_f32_16x16x128_f8f6f4(
                    a[i], b[j], acc[i][j], 0 /*A=e4m3*/, 0 /*B=e4m3*/,
                    0, 0x7F7F7F7F, 0, 0x7F7F7F7F);
        __syncthreads();
    }

    const int col = lane & 15;         // B-row offset within 16-tile
    const int rbase = (lane >> 4) * 4; // first of 4 consecutive A-rows

    if (EPI == EPI_EXP) {
        // P[z][q][key] = fp8(exp(acc*alpha)/16) packed u32; rsum[q] += sum e
        u8* P = (u8*)C0 + z * bsC;
        float* rsum = (float*)C1 + z * 2048;
#pragma unroll
        for (int j = 0; j < 4; j++) {
            const int Cq = n0 + wn * 64 + j * 16 + col;
            float part = 0.f;
#pragma unroll
            for (int i = 0; i < 4; i++) {
                const int R0 = m0 + wm * 64 + i * 16 + rbase;
                float e0 = __expf(acc[i][j][0] * alpha);
                float e1 = __expf(acc[i][j][1] * alpha);
                float e2 = __expf(acc[i][j][2] * alpha);
                float e3 = __expf(acc[i][j][3] * alpha);
                part += (e0 + e1) + (e2 + e3);
                *(u32*)(P + (long long)Cq * ldC + R0) =
                    pack_f8x4(e0 * 0.0625f, e1 * 0.0625f,
                              e2 * 0.0625f, e3 * 0.0625f);
            }
            part += __shfl_xor(part, 16);
            part += __shfl_xor(part, 32);
            if (lane < 16) atomicAdd(&rsum[Cq], part);
        }
        return;
    }

    if (EPI == EPI_EXPF32) {
        // E[token][class] = exp(acc*alpha) float4; rsum[token] += sum
        float* Cw = (float*)C0;
        float* rsum = (float*)C1;
#pragma unroll
        for (int j = 0; j < 4; j++) {
            const int Cq = n0 + wn * 64 + j * 16 + col;
            float part = 0.f;
#pragma unroll
            for (int i = 0; i < 4; i++) {
                const int R0 = m0 + wm * 64 + i * 16 + rbase;
                float4 e;
                e.x = __expf(acc[i][j][0] * alpha);
                e.y = __expf(acc[i][j][1] * alpha);
                e.z = __expf(acc[i][j][2] * alpha);
                e.w = __expf(acc[i][j][3] * alpha);
                part += (e.x + e.y) + (e.z + e.w);
                *(float4*)(Cw + (long long)Cq * ldC + R0) = e;
            }
            part += __shfl_xor(part, 16);
            part += __shfl_xor(part, 32);
            if (lane < 16) atomicAdd(&rsum[Cq], part);
        }
        return;
    }

#pragma unroll
    for (int j = 0; j < 4; j++) {
        const int Cq = n0 + wn * 64 + j * 16 + col;
        float inv;
        if (EPI == EPI_PV) {
            const float* rsum = (const float*)C1 + z * 2048;
            inv = alpha / rsum[Cq];
        }
#pragma unroll
        for (int i = 0; i < 4; i++) {
            const int R0 = m0 + wm * 64 + i * 16 + rbase;
            if (EPI == EPI_F8) {
                u8* C = (u8*)C0 + z * bsC;
                *(u32*)(C + (long long)Cq * ldC + R0) =
                    pack_f8x4(acc[i][j][0] * alpha, acc[i][j][1] * alpha,
                              acc[i][j][2] * alpha, acc[i][j][3] * alpha);
            } else if (EPI == EPI_PV) {
                u8* C = (u8*)C0 + z * bsC;
                float v[4];
#pragma unroll
                for (int r = 0; r < 4; r++) {
                    float t = acc[i][j][r] * inv;
                    v[r] = (t / (1.f + __expf(-t))) * beta;   // silu * beta
                }
                *(u32*)(C + (long long)Cq * ldC + R0) =
                    pack_f8x4(v[0], v[1], v[2], v[3]);
            } else { // EPI_RV: A-rows 0..1023 -> R (alpha), 1024.. -> V^T (beta)
                const int seg = R0 >> 10;
                const int db = R0 & 1023;
                if (seg == 1) {
                    // V^T[bb][d][token], byte scatter over 4 d-rows
                    const int bb = Cq >> 11, tt = Cq & 2047;
                    u8* VTp = (u8*)C2;
#pragma unroll
                    for (int r = 0; r < 4; r++)
                        VTp[(long long)bb * (1024LL * 2048) +
                            (long long)(db + r) * 2048 + tt] =
                            cvt_f8(acc[i][j][r] * beta);
                } else {
                    u8* C = (u8*)C0;
                    *(u32*)(C + (long long)Cq * 1024 + db) =
                        pack_f8x4(acc[i][j][0] * alpha, acc[i][j][1] * alpha,
                                  acc[i][j][2] * alpha, acc[i][j][3] * alpha);
                }
            }
        }
    }
}

// Fused convert: blocks 0..8191 = x -> fp8 (scale 8); 8192..12287 = wv1|wv2|
// fc1|fc2 -> fp8 (scale 256); 12288..13311 = transpose-convert wq1|wk1|wq2|
// wk2 -> fp8^T (scale 256, 64x64 tiles); blocks 0..23 also zero the 3 rsum
// buffers (24576 floats at rz).
__global__ __launch_bounds__(256) void convert_fused(
    const float* x, const float* wv1, const float* wv2, const float* fc1,
    const float* fc2, const float* wq1, const float* wk1, const float* wq2,
    const float* wk2, u8* __restrict__ ax, u8* __restrict__ bproj,
    u8* __restrict__ wfc, u8* __restrict__ wqT, float* __restrict__ rz)
{
    const int bid = blockIdx.x;
    if (bid < 24) {
        float4 zero = {0.f, 0.f, 0.f, 0.f};
        *(float4*)(rz + ((long long)bid * 256 + threadIdx.x) * 4) = zero;
    }
    if (bid >= 12288) {
        // transpose path (old convert_t): 256 tiles per matrix
        const int idx2 = bid - 12288;
        const float* srcs[4] = {wq1, wk1, wq2, wk2};
        const float* src = srcs[idx2 >> 8];
        u8* dst = wqT + (long long)(idx2 >> 8) * (1 << 20);
        const int tile = idx2 & 255;
        const int q0 = (tile & 15) * 64, d0 = (tile >> 4) * 64;
        const int qq = (threadIdx.x & 15) * 4, dd = (threadIdx.x >> 4) * 4;
        float4 v[4];
#pragma unroll
        for (int s = 0; s < 4; s++)
            v[s] = *(const float4*)(src + (long long)(q0 + qq + s) * 1024 + d0 + dd);
        const float* vf = (const float*)v;   // vf[s*4 + r]
#pragma unroll
        for (int r = 0; r < 4; r++)
            *(u32*)(dst + (long long)(d0 + dd + r) * 1024 + q0 + qq) =
                pack_f8x4(vf[0 * 4 + r] * 256.f, vf[1 * 4 + r] * 256.f,
                          vf[2 * 4 + r] * 256.f, vf[3 * 4 + r] * 256.f);
        return;
    }
    const float* src;
    u8* dst;
    float scale;
    long long i;
    if (bid < 8192) {
        src = x; dst = ax; scale = 8.f;
        i = ((long long)bid * 256 + threadIdx.x) * 4;
    } else {
        const int idx = bid - 8192;
        const int wi = idx >> 10;
        const float* srcs[4] = {wv1, wv2, fc1, fc2};
        // wv1 -> Bproj[0] rows 1024+, wv2 -> Bproj[1] rows 1024+, fc -> Wfc
        u8* dsts[4] = {bproj + (1 << 20), bproj + 3 * (1 << 20),
                       wfc, wfc + (1 << 20)};
        src = srcs[wi]; dst = dsts[wi]; scale = 256.f;
        i = (((long long)(idx & 1023)) * 256 + threadIdx.x) * 4;
    }
    float4 v = *(const float4*)(src + i);
    *(u32*)(dst + i) = pack_f8x4(v.x * scale, v.y * scale,
                                 v.z * scale, v.w * scale);
}

// out[row][c] = e[row][c] / rsum[row]  (1024 cols, fp32)
__global__ __launch_bounds__(256) void normalize_1024(
    const float* __restrict__ e, const float* __restrict__ rsum,
    float* __restrict__ out)
{
    const long long row = blockIdx.x;
    const float inv = 1.0f / rsum[row];
    const float* p = e + row * 1024;
    float* o = out + row * 1024;
    float4 v = *(const float4*)(p + threadIdx.x * 4);
    float4 ov;
    ov.x = v.x * inv; ov.y = v.y * inv; ov.z = v.z * inv; ov.w = v.w * inv;
    *(float4*)(o + threadIdx.x * 4) = ov;
}

extern "C" void kernel_launch(void* const* d_in, const int* in_sizes, int n_in,
                              void* d_out, int out_size, void* d_ws, size_t ws_size,
                              hipStream_t stream)
{
    float* out = (float*)d_out;

    constexpr int Bt = 4, S = 2048, D = 1024;
    constexpr int M = Bt * S;                  // 8192
    const long long MD = (long long)M * D;     // 8,388,608
    const long long DD = (long long)D * D;
    const long long SD = (long long)S * D;
    const long long SS = (long long)S * S;

    // ws: Af 8MB | Bproj 2x2MB | WqT 4x1MB | Wfc 2x1MB | Rf 8MB | VT 8MB |
    // Pf 16MB | Hs 8MB | SC fp32 32MB | rsum0|1|2
    u8* Af = (u8*)d_ws;
    u8* Bproj = Af + MD;                 // [2][2048][1024]: WqkT | wv
    u8* WqT = Bproj + 2 * 2048 * 1024;   // wq1T | wk1T | wq2T | wk2T
    u8* Wfc = WqT + 4 * DD;              // fc1 | fc2
    u8* Rf = Wfc + 2 * DD;
    u8* VT = Rf + MD;
    u8* Pf = VT + MD;
    u8* Hs = Pf + (long long)Bt * SS;
    float* SC = (float*)(Hs + MD);
    float* rsum0 = SC + MD;
    float* rsum1 = rsum0 + M;
    float* rsum2 = rsum1 + M;

    const dim3 blk(256);

    const float SOFT = 0.08838834764831845f; // 1/sqrt(128)
    // scale-fold alphas (all pow2 exact):
    const float a_d1   = 1.f / 64.f;               // WqkT: 256*256 -> 1024
    const float a_R[2] = {1.f / 512.f, 1.f / 1024.f};  // R1: 8*1024->16; R2: 256*1024->256
    const float b_V[2] = {1.f / 256.f, 1.f / 64.f};    // V1: 8*256->8; V2: 256*256->1024
    const float a_qk[2] = {SOFT / 128.f, SOFT / 65536.f}; // R*act scales
    const float a_pv[2] = {2.0f, 1.f / 64.f};      // 16 / V-scale, then /rsum
    const float b_pv[2] = {256.f, 65536.f};        // Hs store scale
    const float a_fc[2] = {256.f / 65536.f, 1.f / 16777216.f};

    convert_fused<<<dim3(13312), blk, 0, stream>>>(
        (const float*)d_in[0], (const float*)d_in[3], (const float*)d_in[7],
        (const float*)d_in[4], (const float*)d_in[8], (const float*)d_in[1],
        (const float*)d_in[2], (const float*)d_in[5], (const float*)d_in[6],
        Af, Bproj, Wfc, WqT, rsum0);
    // Bproj[z] rows 0..1023 = WqkT_z = P(A=wqT_z, B=wkT_z), stored scale 1024
    gemm_fp8<EPI_F8><<<dim3(8, 8, 2), blk, 0, stream>>>(
        WqT, WqT + DD, Bproj, nullptr, nullptr, D, D, D, D,
        2 * DD, 2 * DD, (long long)2048 * 1024, a_d1, 0.f);

    const dim3 grv(M / 128, 2048 / 128, 1);    // [R|V] projection (64,16)
    const dim3 gqk(S / 128, S / 128, Bt);      // scores: x = queries, y = keys
    const dim3 gpv(S / 128, D / 128, Bt);      // x = tokens, y = d-tiles
    const dim3 gw(M / 128, D / 128, 1);        // fc GEMMs (64,8)

    for (int layer = 0; layer < 2; layer++) {
        const u8* bp = Bproj + (long long)layer * 2048 * 1024;
        const u8* fc = Wfc + (long long)layer * DD;
        float* rsum = layer ? rsum1 : rsum0;

        // R[t][j] (Rf, packed u32) and V^T[b][d][t] (VT, scatter)
        gemm_fp8<EPI_RV><<<grv, blk, 0, stream>>>(
            bp, Af, Rf, nullptr, VT, D, D, D, D, 0, 0, 0,
            a_R[layer], b_V[layer]);
        // P[z][q][key] = fp8(exp(score)/16); rsum[q] = sum exp.
        // keys side = activations themselves (Af), queries side = R.
        gemm_fp8<EPI_EXP><<<gqk, blk, 0, stream>>>(
            Af, Rf, Pf, rsum, nullptr, D, D, D, S, SD, SD, SS,
            a_qk[layer], 0.f);
        // Hs[token][d] = fp8(silu(P@V / rsum) * b_pv)
        gemm_fp8<EPI_PV><<<gpv, blk, 0, stream>>>(
            VT, Pf, Hs, rsum, nullptr, S, S, S, D,
            (long long)D * S, SS, SD, a_pv[layer], b_pv[layer]);
        if (layer == 0) {
            gemm_fp8<EPI_F8><<<gw, blk, 0, stream>>>(
                fc, Hs, Af, nullptr, nullptr, D, D, D, D, 0, 0, 0,
                a_fc[0], 0.f);
        } else {
            gemm_fp8<EPI_EXPF32><<<gw, blk, 0, stream>>>(
                fc, Hs, SC, rsum2, nullptr, D, D, D, D, 0, 0, 0,
                a_fc[1], 0.f);
        }
    }

    normalize_1024<<<dim3(M), blk, 0, stream>>>(SC, rsum2, out);
}